// Round 1
// baseline (142.591 us; speedup 1.0000x reference)
//
#include <hip/hip_runtime.h>
#include <math.h>

#define HH 256
#define WW 256
#define BB 8
#define MM 256
#define NN (HH * WW)

__device__ __constant__ const float EPSI = 1e-6f;
// MAX_DIST = sqrt(256^2 + 256^2) = 256*sqrt(2)
__device__ __constant__ const float MAXD = 362.03867196751236f;
// EPS / MAX_DIST
__device__ __constant__ const float EPS_OVER_MAXD = 1e-6f / 362.03867196751236f;

// ---------------------------------------------------------------------------
// init: gmin[B*M] = +inf (bit pattern 0x7F800000), sums[B*2] = 0
// ---------------------------------------------------------------------------
__global__ __launch_bounds__(256) void whd_init(float* __restrict__ sums,
                                                int* __restrict__ gmin) {
    int t = blockIdx.x * 256 + threadIdx.x;
    if (t < BB * 2) sums[t] = 0.0f;
    if (t < BB * MM) gmin[t] = 0x7F800000;  // +inf
}

// ---------------------------------------------------------------------------
// main: one block = 256 pixels of one batch. LDS-staged GT points.
//   term1 partials: sum_p, sum_{p*min_m d}  -> global atomicAdd per block
//   term2 partials: per-m column min of (sqrt(d2)+EPS)*inv_denom_n
//                   -> shared int atomicMin (rotated m => conflict-free),
//                      then one global atomicMin per (b,m) per block
// ---------------------------------------------------------------------------
__global__ __launch_bounds__(256) void whd_main(const float* __restrict__ pm,
                                                const float* __restrict__ gt,
                                                const float* __restrict__ osz,
                                                float* __restrict__ sums,
                                                int* __restrict__ gmin) {
    __shared__ float2 sgt[MM];   // normalized GT coords (y, x)
    __shared__ int    smin[MM];  // per-m column min (float bits, nonneg)
    __shared__ float  swred[8];  // 4 waves x 2 partial sums

    const int b   = blockIdx.y;
    const int tid = threadIdx.x;

    // norm factor (== 1 for the given inputs, but implement generally)
    const float nfY = osz[b * 2 + 0] * (1.0f / HH);
    const float nfX = osz[b * 2 + 1] * (1.0f / WW);

    // stage GT points (one per thread; M == blockDim)
    {
        const float gy = gt[(b * MM + tid) * 2 + 0] * nfY;
        const float gx = gt[(b * MM + tid) * 2 + 1] * nfX;
        sgt[tid]  = make_float2(gy, gx);
        smin[tid] = 0x7F800000;  // +inf
    }
    __syncthreads();

    // this thread's pixel
    const int   n = blockIdx.x * 256 + tid;
    const float y = (float)(n >> 8) * nfY;   // W == 256
    const float x = (float)(n & 255) * nfX;
    const float p = pm[b * NN + n];

    const float p2      = p * p;
    const float p4      = p2 * p2;           // p^ALPHA, ALPHA=4
    const float invden  = 1.0f / (p4 + EPS_OVER_MAXD);

    float mind2 = INFINITY;

    #pragma unroll 4
    for (int mm = 0; mm < MM; ++mm) {
        const int m = (mm + tid) & (MM - 1);      // rotate: lanes hit distinct m
        const float2 g = sgt[m];
        const float dy = y - g.x;
        const float dx = x - g.y;
        const float d2 = dy * dy + dx * dx;
        mind2 = fminf(mind2, d2);
        const float v = (sqrtf(d2) + EPSI) * invden;   // >= 0 always
        atomicMin(&smin[m], __float_as_int(v));        // int-order == float-order for >=0
    }

    // term1 partials: block reduce (p, p*min_d)
    float v0 = p;
    float v1 = p * sqrtf(mind2);
    #pragma unroll
    for (int off = 32; off; off >>= 1) {
        v0 += __shfl_down(v0, off, 64);
        v1 += __shfl_down(v1, off, 64);
    }
    const int wv = tid >> 6;
    if ((tid & 63) == 0) { swred[wv * 2] = v0; swred[wv * 2 + 1] = v1; }
    __syncthreads();   // also guarantees all smin atomics above are done
    if (tid == 0) {
        const float s0 = swred[0] + swred[2] + swred[4] + swred[6];
        const float s1 = swred[1] + swred[3] + swred[5] + swred[7];
        atomicAdd(&sums[b * 2 + 0], s0);
        atomicAdd(&sums[b * 2 + 1], s1);
    }

    // merge per-m minima into global
    atomicMin(&gmin[b * MM + tid], smin[tid]);
}

// ---------------------------------------------------------------------------
// final: out = mean_b(sum_pd / (sum_p + EPS)) + mean_{b,m}(clip(min, 0, MAXD))
// ---------------------------------------------------------------------------
__global__ __launch_bounds__(256) void whd_final(const float* __restrict__ sums,
                                                 const int* __restrict__ gmin,
                                                 float* __restrict__ out) {
    __shared__ float sw[4];
    const int tid = threadIdx.x;

    float acc = 0.0f;
    #pragma unroll
    for (int b = 0; b < BB; ++b) {
        float v = __int_as_float(gmin[b * MM + tid]);
        v = fminf(fmaxf(v, 0.0f), MAXD);
        acc += v;
    }
    #pragma unroll
    for (int off = 32; off; off >>= 1) acc += __shfl_down(acc, off, 64);
    if ((tid & 63) == 0) sw[tid >> 6] = acc;
    __syncthreads();
    if (tid == 0) {
        const float t2 = (sw[0] + sw[1] + sw[2] + sw[3]) * (1.0f / (BB * MM));
        float t1 = 0.0f;
        #pragma unroll
        for (int b = 0; b < BB; ++b)
            t1 += sums[b * 2 + 1] / (sums[b * 2 + 0] + EPSI);
        out[0] = t1 * (1.0f / BB) + t2;
    }
}

// ---------------------------------------------------------------------------
extern "C" void kernel_launch(void* const* d_in, const int* in_sizes, int n_in,
                              void* d_out, int out_size, void* d_ws, size_t ws_size,
                              hipStream_t stream) {
    const float* pm  = (const float*)d_in[0];   // [B, H, W]
    const float* gt  = (const float*)d_in[1];   // [B, M, 2]
    const float* osz = (const float*)d_in[2];   // [B, 2]
    float* out = (float*)d_out;

    float* sums = (float*)d_ws;                       // B*2 floats = 64 B
    int*   gmin = (int*)((char*)d_ws + 64);           // B*M ints = 8 KiB

    whd_init<<<(BB * MM + 255) / 256, 256, 0, stream>>>(sums, gmin);

    dim3 grid(NN / 256, BB);
    whd_main<<<grid, 256, 0, stream>>>(pm, gt, osz, sums, gmin);

    whd_final<<<1, 256, 0, stream>>>(sums, gmin, out);
}